// Round 1
// baseline (128.074 us; speedup 1.0000x reference)
//
#include <hip/hip_runtime.h>

// DAS beamforming: out[b,z,x,k] = sum_c lerp(rf[b,c], delay(b,c,z,x))[k]
// Design: block = (batch, 2048-pixel tile, 32-channel chunk). Each channel's
// 32 KiB rf slice is async-staged (global_load_lds, double-buffered) into LDS
// with an XOR-swizzled layout to kill ds_read_b128 bank conflicts, gathered
// per-pixel, accumulated in registers over 32 channels, then atomicAdd'd.

#define NBATCH 2
#define NC 128
#define NS 2048
#define NZ 256
#define NX 256
#define NK 4
#define NM (NZ * NX)                         // 65536 pixels per batch

#define THREADS 512
#define PX_PER_THREAD 4
#define PX_PER_BLOCK (THREADS * PX_PER_THREAD)  // 2048
#define C_PER_BLOCK 32
#define N_CHUNKS (NC / C_PER_BLOCK)          // 4
#define N_TILES (NM / PX_PER_BLOCK)          // 32
#define NBLOCKS (NBATCH * N_TILES * N_CHUNKS)   // 256 = 1 block/CU
#define SLICE_CHUNKS (NS * NK / 4)           // 2048 float4 chunks = 32 KiB

// XOR swizzle within each 128-B row (8 chunks): involution, breaks the
// period-8 bank-quad aliasing of stride-4-sample gathers.
__device__ __forceinline__ int swz(int c) {
    return (c & ~7) | ((c ^ (c >> 3)) & 7);
}

// Stage one channel slice (32 KiB) global->LDS async. global_load_lds writes
// LDS at wave-uniform base + lane*16, so we permute the SOURCE address by the
// (involutive) swizzle: LDS chunk d receives global chunk swz(d).
__device__ __forceinline__ void stage_channel(const float* slice, float4* lbuf, int t) {
#pragma unroll
    for (int r = 0; r < SLICE_CHUNKS / THREADS; ++r) {
        const int d = r * THREADS + t;
        const int sc = swz(d);
        __builtin_amdgcn_global_load_lds(
            (const __attribute__((address_space(1))) void*)(slice + (size_t)sc * 4),
            (__attribute__((address_space(3))) void*)(lbuf + d),
            16, 0, 0);
    }
}

__global__ __launch_bounds__(THREADS, 2) void das_kernel(
    const float* __restrict__ rf, const float* __restrict__ g,
    const float* __restrict__ pr, const float* __restrict__ p,
    float* __restrict__ out)
{
    __shared__ float4 sbuf[2][SLICE_CHUNKS];   // 2 x 32 KiB double buffer

    const int bid   = blockIdx.x;
    const int chunk = bid & (N_CHUNKS - 1);
    const int tile  = (bid >> 2) & (N_TILES - 1);
    const int b     = bid >> 7;
    const int t     = threadIdx.x;
    const int px0   = tile * PX_PER_BLOCK;

    const float c0v = p[b * 4 + 0];
    const float fsv = p[b * 4 + 1];
    const float t0v = p[b * 4 + 2];
    const float scale = fsv / c0v;            // samples per meter
    const float sb0   = scale * t0v;

    // Pixel coords for this thread's 4 pixels (consecutive lanes = consecutive x)
    float gx[PX_PER_THREAD], gy[PX_PER_THREAD], gzv[PX_PER_THREAD];
#pragma unroll
    for (int j = 0; j < PX_PER_THREAD; ++j) {
        const int m = px0 + j * THREADS + t;
        const float* gp = g + ((size_t)b * NM + m) * 3;
        gx[j]  = gp[0];
        gy[j]  = gp[1];
        gzv[j] = gp[2];
    }

    float acc[PX_PER_THREAD][NK];
#pragma unroll
    for (int j = 0; j < PX_PER_THREAD; ++j)
#pragma unroll
        for (int k = 0; k < NK; ++k) acc[j][k] = 0.0f;

    const int ch0 = chunk * C_PER_BLOCK;
    const float* slice0 = rf + ((size_t)(b * NC + ch0)) * NS * NK;

    stage_channel(slice0, &sbuf[0][0], t);

    for (int cc = 0; cc < C_PER_BLOCK; ++cc) {
        // Barrier drains the async stage into sbuf[cc&1] (vmcnt(0) before
        // s_barrier) and guarantees everyone finished reading sbuf[(cc+1)&1]
        // in the previous iteration before we overwrite it below.
        __syncthreads();
        if (cc + 1 < C_PER_BLOCK)
            stage_channel(slice0 + (size_t)(cc + 1) * NS * NK,
                          &sbuf[(cc + 1) & 1][0], t);  // in flight during compute

        const float4* lb = &sbuf[cc & 1][0];
        const int ch = ch0 + cc;
        const float* prp = pr + ((size_t)b * NC + ch) * 3;
        const float prx = prp[0], pry = prp[1], prz = prp[2];

#pragma unroll
        for (int j = 0; j < PX_PER_THREAD; ++j) {
            const float dx = gx[j]  - prx;
            const float dy = gy[j]  - pry;
            const float dz = gzv[j] - prz;
            const float drx = sqrtf(dx * dx + dy * dy + dz * dz);
            float s = sb0 + scale * (drx + gzv[j]);       // fs*(t0+d)/c0
            s = fminf(fmaxf(s, 0.0f), (float)(NS - 1));   // clamp to grid
            int i0 = (int)floorf(s);
            i0 = min(max(i0, 0), NS - 2);
            const float w = s - (float)i0;
            const float4 y0 = lb[swz(i0)];
            const float4 y1 = lb[swz(i0 + 1)];
            acc[j][0] += y0.x + w * (y1.x - y0.x);
            acc[j][1] += y0.y + w * (y1.y - y0.y);
            acc[j][2] += y0.z + w * (y1.z - y0.z);
            acc[j][3] += y0.w + w * (y1.w - y0.w);
        }
    }

    // One atomic add per (pixel,k) per channel-chunk: 4 chunks contend per cell.
    float* ob = out + (size_t)b * NM * NK;
#pragma unroll
    for (int j = 0; j < PX_PER_THREAD; ++j) {
        const int m = px0 + j * THREADS + t;
        float* op = ob + (size_t)m * NK;
        atomicAdd(op + 0, acc[j][0]);
        atomicAdd(op + 1, acc[j][1]);
        atomicAdd(op + 2, acc[j][2]);
        atomicAdd(op + 3, acc[j][3]);
    }
}

extern "C" void kernel_launch(void* const* d_in, const int* in_sizes, int n_in,
                              void* d_out, int out_size, void* d_ws, size_t ws_size,
                              hipStream_t stream) {
    (void)in_sizes; (void)n_in; (void)d_ws; (void)ws_size;
    const float* rf = (const float*)d_in[0];
    const float* g  = (const float*)d_in[1];
    const float* pr = (const float*)d_in[2];
    const float* p  = (const float*)d_in[3];
    float* out = (float*)d_out;

    // Output is poisoned 0xAA before every launch; atomics need zeros.
    hipMemsetAsync(d_out, 0, (size_t)out_size * sizeof(float), stream);
    das_kernel<<<NBLOCKS, THREADS, 0, stream>>>(rf, g, pr, p, out);
}

// Round 2
// 93.100 us; speedup vs baseline: 1.3757x; 1.3757x over previous
//
#include <hip/hip_runtime.h>

// DAS beamforming: out[b,z,x,k] = sum_c lerp(rf[b,c], delay(b,c,z,x))[k]
// Round 2: - no memset/atomics: per-chunk partials into d_ws, reduce kernel sums
//          - 1024-thread blocks -> 16 waves/CU (was 8), latency hiding
//          - dropped XOR swizzle (gathers are random; measured conflicts 0.13 cyc/read)
//          - raw v_sqrt_f32, hoisted per-pixel delay base, paired ds_read via offset:16

#define NBATCH 2
#define NC 128
#define NS 2048
#define NK 4
#define NM 65536                              // Nz*Nx pixels per batch

#define THREADS 1024
#define PX_PER_THREAD 2
#define PX_PER_BLOCK (THREADS * PX_PER_THREAD)   // 2048
#define C_PER_BLOCK 32
#define N_CHUNKS (NC / C_PER_BLOCK)           // 4
#define N_TILES (NM / PX_PER_BLOCK)           // 32
#define NBLOCKS (NBATCH * N_TILES * N_CHUNKS) // 256 = 1 block/CU, 16 waves/CU
#define SLICE_CHUNKS (NS * NK / 4)            // 2048 float4 = 32 KiB per channel

// Stage one channel slice (32 KiB) global->LDS async (16 B/lane, lane-sequential
// LDS dest as the HW requires).
__device__ __forceinline__ void stage_channel(const float* slice, float4* lbuf, int t) {
#pragma unroll
    for (int r = 0; r < SLICE_CHUNKS / THREADS; ++r) {
        const int d = r * THREADS + t;
        __builtin_amdgcn_global_load_lds(
            (const __attribute__((address_space(1))) void*)(slice + (size_t)d * 4),
            (__attribute__((address_space(3))) void*)(lbuf + d),
            16, 0, 0);
    }
}

template <bool ATOMIC>
__global__ __launch_bounds__(THREADS, 4) void das_kernel(
    const float* __restrict__ rf, const float* __restrict__ g,
    const float* __restrict__ pr, const float* __restrict__ p,
    float* __restrict__ dst)   // ATOMIC ? out : partials ws
{
    __shared__ float4 sbuf[2][SLICE_CHUNKS];   // 2 x 32 KiB double buffer

    const int bid   = blockIdx.x;
    const int chunk = bid & (N_CHUNKS - 1);
    const int tile  = (bid >> 2) & (N_TILES - 1);
    const int b     = bid >> 7;
    const int t     = threadIdx.x;
    const int px0   = tile * PX_PER_BLOCK;

    const float c0v = p[b * 4 + 0];
    const float fsv = p[b * 4 + 1];
    const float t0v = p[b * 4 + 2];
    const float scale = fsv / c0v;            // samples per meter
    const float sb0   = scale * t0v;

    // This thread's pixels (consecutive lanes = consecutive pixels -> coalesced)
    float gx[PX_PER_THREAD], gy[PX_PER_THREAD], gzv[PX_PER_THREAD], sbase[PX_PER_THREAD];
#pragma unroll
    for (int j = 0; j < PX_PER_THREAD; ++j) {
        const int m = px0 + j * THREADS + t;
        const float* gp = g + ((size_t)b * NM + m) * 3;
        gx[j]  = gp[0];
        gy[j]  = gp[1];
        gzv[j] = gp[2];
        sbase[j] = sb0 + scale * gzv[j];      // fs*(t0 + d_tx)/c0 hoisted
    }

    float4 acc[PX_PER_THREAD];
#pragma unroll
    for (int j = 0; j < PX_PER_THREAD; ++j) acc[j] = make_float4(0.f, 0.f, 0.f, 0.f);

    const int ch0 = chunk * C_PER_BLOCK;
    const float* slice0 = rf + ((size_t)(b * NC + ch0)) * NS * NK;

    stage_channel(slice0, &sbuf[0][0], t);

    for (int cc = 0; cc < C_PER_BLOCK; ++cc) {
        // Drains the stage into sbuf[cc&1] (vmcnt(0) before s_barrier) and
        // protects sbuf[(cc+1)&1] from overwrite while still being read.
        __syncthreads();
        if (cc + 1 < C_PER_BLOCK)
            stage_channel(slice0 + (size_t)(cc + 1) * NS * NK,
                          &sbuf[(cc + 1) & 1][0], t);  // in flight during compute

        const float4* lb = &sbuf[cc & 1][0];
        const float* prp = pr + ((size_t)(b * NC + ch0 + cc)) * 3;
        const float prx = prp[0], pry = prp[1], prz = prp[2];

#pragma unroll
        for (int j = 0; j < PX_PER_THREAD; ++j) {
            const float dx = gx[j]  - prx;
            const float dy = gy[j]  - pry;
            const float dz = gzv[j] - prz;
            const float drx = __builtin_amdgcn_sqrtf(fmaf(dx, dx, fmaf(dy, dy, dz * dz)));
            float s = fmaf(scale, drx, sbase[j]);         // fractional sample index
            s = fminf(fmaxf(s, 0.0f), (float)(NS - 1));   // clamp (v_med3)
            const float fi = fminf(floorf(s), (float)(NS - 2));
            const float w  = s - fi;
            const float wm = 1.0f - w;
            const int i0 = (int)fi;
            const float4 y0 = lb[i0];                     // same vaddr,
            const float4 y1 = lb[i0 + 1];                 // offset:16
            acc[j].x = fmaf(y0.x, wm, fmaf(y1.x, w, acc[j].x));
            acc[j].y = fmaf(y0.y, wm, fmaf(y1.y, w, acc[j].y));
            acc[j].z = fmaf(y0.z, wm, fmaf(y1.z, w, acc[j].z));
            acc[j].w = fmaf(y0.w, wm, fmaf(y1.w, w, acc[j].w));
        }
    }

    if (ATOMIC) {
        float* ob = dst + (size_t)b * NM * NK;
#pragma unroll
        for (int j = 0; j < PX_PER_THREAD; ++j) {
            const int m = px0 + j * THREADS + t;
            float* op = ob + (size_t)m * NK;
            atomicAdd(op + 0, acc[j].x);
            atomicAdd(op + 1, acc[j].y);
            atomicAdd(op + 2, acc[j].z);
            atomicAdd(op + 3, acc[j].w);
        }
    } else {
        // partial[chunk][b][m] as float4 — disjoint per block, plain stores
        float4* pw = (float4*)dst + (size_t)(chunk * NBATCH + b) * NM;
#pragma unroll
        for (int j = 0; j < PX_PER_THREAD; ++j) {
            const int m = px0 + j * THREADS + t;
            pw[m] = acc[j];
        }
    }
}

// out[i] = sum over 4 chunk partials; i indexes float4 over [B*NM)
__global__ __launch_bounds__(256) void reduce_kernel(
    const float4* __restrict__ part, float4* __restrict__ out)
{
    const int i = blockIdx.x * 256 + threadIdx.x;
    float4 a = part[i];
    const float4 b = part[(size_t)1 * NBATCH * NM + i];
    const float4 c = part[(size_t)2 * NBATCH * NM + i];
    const float4 d = part[(size_t)3 * NBATCH * NM + i];
    a.x += b.x + c.x + d.x;
    a.y += b.y + c.y + d.y;
    a.z += b.z + c.z + d.z;
    a.w += b.w + c.w + d.w;
    out[i] = a;
}

extern "C" void kernel_launch(void* const* d_in, const int* in_sizes, int n_in,
                              void* d_out, int out_size, void* d_ws, size_t ws_size,
                              hipStream_t stream) {
    (void)in_sizes; (void)n_in;
    const float* rf = (const float*)d_in[0];
    const float* g  = (const float*)d_in[1];
    const float* pr = (const float*)d_in[2];
    const float* p  = (const float*)d_in[3];
    float* out = (float*)d_out;

    const size_t need = (size_t)N_CHUNKS * NBATCH * NM * NK * sizeof(float); // 8 MB
    if (ws_size >= need) {
        das_kernel<false><<<NBLOCKS, THREADS, 0, stream>>>(rf, g, pr, p, (float*)d_ws);
        reduce_kernel<<<(NBATCH * NM) / 256, 256, 0, stream>>>((const float4*)d_ws,
                                                               (float4*)out);
    } else {
        hipMemsetAsync(d_out, 0, (size_t)out_size * sizeof(float), stream);
        das_kernel<true><<<NBLOCKS, THREADS, 0, stream>>>(rf, g, pr, p, out);
    }
}